// Round 4
// baseline (55.939 us; speedup 1.0000x reference)
//
#include <hip/hip_runtime.h>

// Antecedents: ant[i, r] = prod_j m_j[i, ri[r][j]], N=16384, n_sets=5^5,
// R = 3125, r = a*625 + b*125 + c*25 + d*5 + e (meshgrid 'ij').
// Pure streaming-write kernel: 204.8 MB out, 1.6 MB in.
//
// R1: 1 row/block, dword stores           -> 38.1 us (5.38 TB/s)
// R2: 8 rows/block, float4 stores         -> 39.4 us (neutral; width not the limit)
// R3: + nontemporal stores (compile fix: native ext_vector, not HIP float4).
//     Theory: ~10us fixed tail = end-of-kernel L2 writeback flush; NT streams
//     dirty lines out during the kernel.

#define NSAMP 16384
#define NRULE 3125
#define ROWS_PER_BLOCK 8
#define CHUNK_ELEMS (ROWS_PER_BLOCK * NRULE)      // 25000 floats
#define CHUNK_VEC4 (CHUNK_ELEMS / 4)              // 6250 float4 (exact)

using f32x4 = __attribute__((ext_vector_type(4))) float;

__global__ __launch_bounds__(256) void antecedents_kernel(
    const float* __restrict__ m0, const float* __restrict__ m1,
    const float* __restrict__ m2, const float* __restrict__ m3,
    const float* __restrict__ m4, float* __restrict__ out)
{
    __shared__ float p012[ROWS_PER_BLOCK][125];  // m0[a]*m1[b]*m2[c], idx a*25+b*5+c
    __shared__ float p34[ROWS_PER_BLOCK][25];    // m3[d]*m4[e],       idx d*5+e

    const unsigned t = threadIdx.x;
    const unsigned row0 = blockIdx.x * ROWS_PER_BLOCK;

    // Build partial-product tables for the block's 8 rows (1200 entries).
    for (unsigned u = t; u < ROWS_PER_BLOCK * 150u; u += 256u) {
        const unsigned rr = u / 150u;
        const unsigned k = u - rr * 150u;
        const unsigned row = row0 + rr;
        if (k < 125u) {
            const unsigned a = k / 25u;
            const unsigned b = (k / 5u) % 5u;
            const unsigned c = k % 5u;
            p012[rr][k] = m0[row * 5 + a] * m1[row * 5 + b] * m2[row * 5 + c];
        } else {
            const unsigned kk = k - 125u;
            p34[rr][kk] = m3[row * 5 + kk / 5u] * m4[row * 5 + kk % 5u];
        }
    }
    __syncthreads();

    // Block's output chunk: 25000 floats starting at a 16B-aligned address.
    f32x4* __restrict__ outv =
        (f32x4*)(out + (size_t)blockIdx.x * CHUNK_ELEMS);

    for (unsigned q = t; q < CHUNK_VEC4; q += 256u) {
        f32x4 v;
        unsigned fe = q * 4u;  // local flat element index
#pragma unroll
        for (int k = 0; k < 4; ++k) {
            const unsigned rr = fe / (unsigned)NRULE;       // local row (magic-mul)
            const unsigned r = fe - rr * (unsigned)NRULE;   // rule index
            const unsigned hi = r / 25u;                    // a*25+b*5+c
            const unsigned lo = r - hi * 25u;               // d*5+e
            v[k] = p012[rr][hi] * p34[rr][lo];
            ++fe;
        }
        __builtin_nontemporal_store(v, &outv[q]);  // global_store_dwordx4 ... nt
    }
}

extern "C" void kernel_launch(void* const* d_in, const int* in_sizes, int n_in,
                              void* d_out, int out_size, void* d_ws, size_t ws_size,
                              hipStream_t stream) {
    const float* m0 = (const float*)d_in[0];
    const float* m1 = (const float*)d_in[1];
    const float* m2 = (const float*)d_in[2];
    const float* m3 = (const float*)d_in[3];
    const float* m4 = (const float*)d_in[4];
    float* out = (float*)d_out;

    antecedents_kernel<<<NSAMP / ROWS_PER_BLOCK, 256, 0, stream>>>(
        m0, m1, m2, m3, m4, out);
}

// Round 5
// 38.069 us; speedup vs baseline: 1.4694x; 1.4694x over previous
//
#include <hip/hip_runtime.h>

// Antecedents: ant[i, r] = prod_j m_j[i, ri[r][j]], N=16384, n_sets=5^5,
// R = 3125, r = a*625 + b*125 + c*25 + d*5 + e (meshgrid 'ij').
// Pure streaming-write kernel: 204.8 MB out, 1.6 MB in.
//
// R1: 1 row/block, dword stores           -> 38.1 us (5.38 TB/s)  << best
// R2: 8 rows/block, float4 stores         -> 39.4 us (neutral; width/WG-count
//     invariant => memory-system + fixed-dispatch floor)
// R3/R4: nontemporal stores               -> 55.9 us (nt bypasses L2 write
//     aggregation on gfx950 — regression; reverted)
// R5: revert to R1. Fitted model across ours + harness fill kernel:
//     steady 7.8 TB/s + ~12 us fixed per-dispatch => 38 us is the floor.

#define NSAMP 16384
#define NRULE 3125

__global__ __launch_bounds__(256) void antecedents_kernel(
    const float* __restrict__ m0, const float* __restrict__ m1,
    const float* __restrict__ m2, const float* __restrict__ m3,
    const float* __restrict__ m4, float* __restrict__ out)
{
    __shared__ float p012[125];  // m0[a]*m1[b]*m2[c], index a*25+b*5+c
    __shared__ float p34[25];    // m3[d]*m4[e],       index d*5+e

    const int i = blockIdx.x;          // sample row
    const unsigned t = threadIdx.x;

    if (t < 125u) {
        const unsigned a = t / 25u;
        const unsigned b = (t / 5u) % 5u;
        const unsigned c = t % 5u;
        p012[t] = m0[i * 5 + a] * m1[i * 5 + b] * m2[i * 5 + c];
    } else if (t < 150u) {
        const unsigned u = t - 125u;
        const unsigned d = u / 5u;
        const unsigned e = u % 5u;
        p34[u] = m3[i * 5 + d] * m4[i * 5 + e];
    }
    __syncthreads();

    float* __restrict__ orow = out + (size_t)i * NRULE;
    // 3125 / 256 -> ~12.2 coalesced dword stores per thread.
    for (unsigned r = t; r < NRULE; r += 256u) {
        const unsigned hi = r / 25u;        // a*25+b*5+c  (magic-mul)
        const unsigned lo = r - hi * 25u;   // d*5+e
        orow[r] = p012[hi] * p34[lo];
    }
}

extern "C" void kernel_launch(void* const* d_in, const int* in_sizes, int n_in,
                              void* d_out, int out_size, void* d_ws, size_t ws_size,
                              hipStream_t stream) {
    const float* m0 = (const float*)d_in[0];
    const float* m1 = (const float*)d_in[1];
    const float* m2 = (const float*)d_in[2];
    const float* m3 = (const float*)d_in[3];
    const float* m4 = (const float*)d_in[4];
    float* out = (float*)d_out;

    antecedents_kernel<<<NSAMP, 256, 0, stream>>>(m0, m1, m2, m3, m4, out);
}